// Round 3
// baseline (8521.707 us; speedup 1.0000x reference)
//
#include <hip/hip_runtime.h>

// Problem constants (match reference)
constexpr int Bsz = 32;
constexpr int T   = 4096;
constexpr int P   = 64;
constexpr int IN  = 128;
constexpr int H   = 256;
constexpr long M  = (long)Bsz * T;   // 131072 rows
constexpr int FS  = 16;              // flag padding stride (ints, 64 B)

// Progress flags live in device-global memory: zero workspace-layout change
// vs the verified R1 kernel (ws = exactly 2*M*H floats). flag==v means
// "rows 0..v-1 of my output stream are globally visible".
__device__ int g_flags[3 * 32 * FS];

__global__ void zero_flags() {
  for (int i = threadIdx.x; i < 3 * 32 * FS; i += 256) g_flags[i] = 0;
}

// ---------------------------------------------------------------------------
// K1: out[m][j] = sum_c X[m][c] * W[j][c] + b1[j] + b2[j]   (layer-1 input GEMM)
// ---------------------------------------------------------------------------
template <int K>
__global__ __launch_bounds__(256) void gemm_pre(
    const float* __restrict__ X, const float* __restrict__ W,
    const float* __restrict__ b1, const float* __restrict__ b2,
    float* __restrict__ out) {
  constexpr int K4 = K / 4;
  __shared__ float4 a4[16][K4];
  __shared__ float  wch[256][33];
  const int tid = threadIdx.x;
  const long m0 = (long)blockIdx.x * 16;

  const float4* X4 = (const float4*)X;
#pragma unroll
  for (int i = 0; i < (16 * K4) / 256; ++i) {
    int idx = tid + 256 * i;
    int r = idx / K4, c = idx % K4;
    a4[r][c] = X4[(m0 + r) * K4 + c];
  }

  const int j = tid;
  const float bsum = b1[j] + b2[j];
  float acc[16];
#pragma unroll
  for (int r = 0; r < 16; ++r) acc[r] = 0.f;

  const float4* W4v = (const float4*)W;
  for (int kc = 0; kc < K4; kc += 8) {
    __syncthreads();
#pragma unroll
    for (int i = 0; i < 8; ++i) {
      int idx = tid + 256 * i;
      int jr = idx >> 3, c = idx & 7;
      float4 t4 = W4v[(long)jr * K4 + kc + c];
      wch[jr][4 * c + 0] = t4.x; wch[jr][4 * c + 1] = t4.y;
      wch[jr][4 * c + 2] = t4.z; wch[jr][4 * c + 3] = t4.w;
    }
    __syncthreads();
#pragma unroll
    for (int i4 = 0; i4 < 8; ++i4) {
      float wx = wch[j][4 * i4 + 0], wy = wch[j][4 * i4 + 1];
      float wz = wch[j][4 * i4 + 2], ww = wch[j][4 * i4 + 3];
#pragma unroll
      for (int r = 0; r < 16; ++r) {
        float4 av = a4[r][kc + i4];
        acc[r] += wx * av.x + wy * av.y + wz * av.z + ww * av.w;
      }
    }
  }
#pragma unroll
  for (int r = 0; r < 16; ++r)
    out[(m0 + r) * H + j] = acc[r] + bsum;
}

// ---------------------------------------------------------------------------
// Cross-WG primitives. Data via AGENT-scope atomics (coherent across the
// non-coherent per-XCD L2s); per-batch progress flags with acquire/release.
// ---------------------------------------------------------------------------
__device__ __forceinline__ float gload(const float* p) {
  return __hip_atomic_load(const_cast<float*>(p), __ATOMIC_RELAXED,
                           __HIP_MEMORY_SCOPE_AGENT);
}
__device__ __forceinline__ void gstore(float* p, float v) {
  __hip_atomic_store(p, v, __ATOMIC_RELAXED, __HIP_MEMORY_SCOPE_AGENT);
}
__device__ __forceinline__ void wait_ge(const int* f, int target, int& seen) {
  if (seen >= target) return;
  int v = __hip_atomic_load(const_cast<int*>(f), __ATOMIC_ACQUIRE,
                            __HIP_MEMORY_SCOPE_AGENT);
  while (v < target) {
    __builtin_amdgcn_s_sleep(8);
    v = __hip_atomic_load(const_cast<int*>(f), __ATOMIC_ACQUIRE,
                          __HIP_MEMORY_SCOPE_AGENT);
  }
  seen = v;
}
__device__ __forceinline__ void publish(int* f, int v) {
  __hip_atomic_store(f, v, __ATOMIC_RELEASE, __HIP_MEMORY_SCOPE_AGENT);
}

// ---------------------------------------------------------------------------
// Shared matvec machinery: (4 j x 16 k) per thread, H=256 per WG.
// lane = jg(bits0-1) x ks(bits2-5); wave wv owns j in [wv*16, wv*16+16).
// h stored in LDS as 16 slices of 16 words padded to stride 20 (bank-clean).
// ---------------------------------------------------------------------------
struct WTile { float4 w[4][4]; };

__device__ __forceinline__ void load_wtile(const float* Wm, int wv, int jg,
                                           int ks, WTile& wt) {
  const float4* W4 = (const float4*)Wm;
#pragma unroll
  for (int r = 0; r < 4; ++r)
#pragma unroll
    for (int q = 0; q < 4; ++q)
      wt.w[r][q] = W4[(long)(wv * 16 + jg * 4 + r) * (H / 4) + ks * 4 + q];
#pragma unroll
  for (int r = 0; r < 4; ++r)
#pragma unroll
    for (int q = 0; q < 4; ++q)
      asm volatile("" : "+v"(wt.w[r][q].x), "+v"(wt.w[r][q].y),
                        "+v"(wt.w[r][q].z), "+v"(wt.w[r][q].w));
}

__device__ __forceinline__ float matvec_reduce(const WTile& wt, const float* hb,
                                               int bit4, int bit8) {
  float4 h0 = *(const float4*)(hb + 0);
  float4 h1 = *(const float4*)(hb + 4);
  float4 h2 = *(const float4*)(hb + 8);
  float4 h3 = *(const float4*)(hb + 12);
  float acc[4] = {0.f, 0.f, 0.f, 0.f};
#pragma unroll
  for (int r = 0; r < 4; ++r) {
    acc[r] += wt.w[r][0].x * h0.x + wt.w[r][0].y * h0.y +
              wt.w[r][0].z * h0.z + wt.w[r][0].w * h0.w;
    acc[r] += wt.w[r][1].x * h1.x + wt.w[r][1].y * h1.y +
              wt.w[r][1].z * h1.z + wt.w[r][1].w * h1.w;
    acc[r] += wt.w[r][2].x * h2.x + wt.w[r][2].y * h2.y +
              wt.w[r][2].z * h2.z + wt.w[r][2].w * h2.w;
    acc[r] += wt.w[r][3].x * h3.x + wt.w[r][3].y * h3.y +
              wt.w[r][3].z * h3.z + wt.w[r][3].w * h3.w;
  }
  __builtin_amdgcn_sched_barrier(0);
  // accumulator-halving butterfly over the 16 ks-lanes
  float t0 = bit4 ? acc[0] : acc[2];
  float t1 = bit4 ? acc[1] : acc[3];
  float r0 = __int_as_float(__builtin_amdgcn_ds_swizzle(__float_as_int(t0), 0x101F));
  float r1 = __int_as_float(__builtin_amdgcn_ds_swizzle(__float_as_int(t1), 0x101F));
  float u0 = (bit4 ? acc[2] : acc[0]) + r0;
  float u1 = (bit4 ? acc[3] : acc[1]) + r1;
  float t2 = bit8 ? u0 : u1;
  float r2 = __int_as_float(__builtin_amdgcn_ds_swizzle(__float_as_int(t2), 0x201F));
  float s  = (bit8 ? u1 : u0) + r2;
  s += __int_as_float(__builtin_amdgcn_ds_swizzle(__float_as_int(s), 0x401F));
  s += __shfl_xor(s, 32, 64);
  return s;
}

// ---------------------------------------------------------------------------
// Role A/B: recurrent scan. ATOMPRE=false: pre stream from prior-kernel buffer
// (plain loads). ATOMPRE=true: pre stream produced live by role M (atomic
// loads gated by inflag). h-row published one step LATE so the store's vmcnt
// drain at the barrier overlaps a full step instead of sitting on the tail.
// ---------------------------------------------------------------------------
template <bool ATOMPRE>
__device__ __forceinline__ void scan_role(
    const float* prebuf, const float* Wm, float* houtb,
    const int* inflag, int* outflag, int b, float (*h_lds)[320]) {
  const int tid = threadIdx.x, lane = tid & 63, wv = tid >> 6;
  const int jg = lane & 3, ks = lane >> 2;
  const int bit4 = lane & 4, bit8 = lane & 8;
  const int jj2 = ((lane >> 1) & 2) | ((lane >> 3) & 1);

  WTile wt; load_wtile(Wm, wv, jg, ks, wt);
  const int  jmine = wv * 16 + jg * 4 + jj2;
  const long base  = (long)b * T * H + jmine;
  const int  wr    = wv * 20 + (jg * 4 + jj2);

  if (tid < 640) ((float*)h_lds)[tid] = 0.f;   // zero both state buffers

  int seen = 0;
  float p0, p1;
  if constexpr (ATOMPRE) {
    wait_ge(inflag, 1, seen); p0 = gload(prebuf + base);
    wait_ge(inflag, 2, seen); p1 = gload(prebuf + base + H);
  } else {
    p0 = prebuf[base]; p1 = prebuf[base + H];
  }
  float hn_prev = 0.f;
  __syncthreads();

#pragma unroll 1
  for (int t = 0; t < T; ++t) {
    if (t > 0 && lane < 16) gstore(houtb + base + (long)(t - 1) * H, hn_prev);
    float p2 = 0.f;
    if (t + 2 < T) {
      if constexpr (ATOMPRE) {
        wait_ge(inflag, t + 3, seen);
        p2 = gload(prebuf + base + (long)(t + 2) * H);
      } else {
        p2 = prebuf[base + (long)(t + 2) * H];
      }
    }
    float s = matvec_reduce(wt, h_lds[t & 1] + ks * 20, bit4, bit8);
    float x = p0 + s;
    float e = __expf(2.f * x);                             // e^{2x}
    float hn = 1.f - 2.f * __builtin_amdgcn_rcpf(e + 1.f); // tanh(x)
    if (lane < 16) h_lds[(t + 1) & 1][wr] = hn;
    hn_prev = hn;
    p0 = p1; p1 = p2;
    __syncthreads();                 // drains step-t gstore (row t-1) + LDS
    if (tid == 0) publish(outflag, t);   // rows <= t-1 visible
  }
  if (lane < 16) gstore(houtb + base + (long)(T - 1) * H, hn_prev);
  __syncthreads();
  if (tid == 0) publish(outflag, T);
}

// ---------------------------------------------------------------------------
// Role M: pre2[t] = W_ih1 @ h1[t] + b_ih1 + b_hh1. Feed-forward stream lagging
// A by >=1 step. h1[t+1] staged coalesced (256 threads) into LDS while
// computing on h1[t]; output row published one step late (same as scan).
// ---------------------------------------------------------------------------
__device__ __forceinline__ void mid_role(
    const float* h1b, const float* Wm, const float* bi, const float* bh,
    float* pre2b, const int* Af, int* Mf, int b, float (*h1s)[320]) {
  const int tid = threadIdx.x, lane = tid & 63, wv = tid >> 6;
  const int jg = lane & 3, ks = lane >> 2;
  const int bit4 = lane & 4, bit8 = lane & 8;
  const int jj2 = ((lane >> 1) & 2) | ((lane >> 3) & 1);

  WTile wt; load_wtile(Wm, wv, jg, ks, wt);
  const int  jmine = wv * 16 + jg * 4 + jj2;
  const long pbase = (long)b * T * H + jmine;
  const float bsum = bi[jmine] + bh[jmine];
  const long hrow  = (long)b * T * H;

  int seen = 0;
  if (tid < 256) {                       // stage h1[0]
    wait_ge(Af, 1, seen);
    float v = gload(h1b + hrow + tid);
    h1s[0][(tid >> 4) * 20 + (tid & 15)] = v;
  }
  float s_prev = 0.f;
  __syncthreads();

#pragma unroll 1
  for (int t = 0; t < T; ++t) {
    if (t > 0 && lane < 16) gstore(pre2b + pbase + (long)(t - 1) * H, s_prev);
    float vn = 0.f; const int tn = t + 1;
    if (tn < T && tid < 256) {
      wait_ge(Af, tn + 1, seen);
      vn = gload(h1b + hrow + (long)tn * H + tid);
    }
    float s = matvec_reduce(wt, h1s[t & 1] + ks * 20, bit4, bit8) + bsum;
    if (tn < T && tid < 256) h1s[tn & 1][(tid >> 4) * 20 + (tid & 15)] = vn;
    s_prev = s;
    __syncthreads();
    if (tid == 0) publish(Mf, t);
  }
  if (lane < 16) gstore(pre2b + pbase + (long)(T - 1) * H, s_prev);
  __syncthreads();
  if (tid == 0) publish(Mf, T);
}

// ---------------------------------------------------------------------------
// Role F: out[b*T+t][p] = sigmoid(h2[t]·fcW[p] + fcb[p]). Streams behind B.
// thread = (p = wv*4+jg) x (k-slice ks): 16 MAC + 4-stage butterfly.
// ---------------------------------------------------------------------------
__device__ __forceinline__ void fc_role(
    const float* h2b, const float* fcWm, const float* fcbv, float* outp,
    const int* Bf, int b, float (*h2s)[320]) {
  const int tid = threadIdx.x, lane = tid & 63, wv = tid >> 6;
  const int jg = lane & 3, ks = lane >> 2;
  const int p = wv * 4 + jg;

  const float4* W4 = (const float4*)fcWm;
  float4 fw[4];
#pragma unroll
  for (int q = 0; q < 4; ++q) fw[q] = W4[(long)p * (H / 4) + ks * 4 + q];
  const float fb = fcbv[p];
  const long hrow  = (long)b * T * H;
  const long obase = (long)b * T * P;

  int seen = 0;
  if (tid < 256) {                       // stage h2[0]
    wait_ge(Bf, 1, seen);
    float v = gload(h2b + hrow + tid);
    h2s[0][(tid >> 4) * 20 + (tid & 15)] = v;
  }
  __syncthreads();

#pragma unroll 1
  for (int t = 0; t < T; ++t) {
    float vn = 0.f; const int tn = t + 1;
    if (tn < T && tid < 256) {
      wait_ge(Bf, tn + 1, seen);
      vn = gload(h2b + hrow + (long)tn * H + tid);
    }
    const float* hb = h2s[t & 1] + ks * 20;
    float4 h0 = *(const float4*)(hb + 0);
    float4 h1 = *(const float4*)(hb + 4);
    float4 h2 = *(const float4*)(hb + 8);
    float4 h3 = *(const float4*)(hb + 12);
    float s = fw[0].x * h0.x + fw[0].y * h0.y + fw[0].z * h0.z + fw[0].w * h0.w
            + fw[1].x * h1.x + fw[1].y * h1.y + fw[1].z * h1.z + fw[1].w * h1.w
            + fw[2].x * h2.x + fw[2].y * h2.y + fw[2].z * h2.z + fw[2].w * h2.w
            + fw[3].x * h3.x + fw[3].y * h3.y + fw[3].z * h3.z + fw[3].w * h3.w;
    s += __int_as_float(__builtin_amdgcn_ds_swizzle(__float_as_int(s), 0x101F));
    s += __int_as_float(__builtin_amdgcn_ds_swizzle(__float_as_int(s), 0x201F));
    s += __int_as_float(__builtin_amdgcn_ds_swizzle(__float_as_int(s), 0x401F));
    s += __shfl_xor(s, 32, 64);
    float xx = s + fb;
    float sig = __builtin_amdgcn_rcpf(1.f + __expf(-xx));
    if (lane < 4) outp[obase + (long)t * P + wv * 4 + lane] = sig;
    if (tn < T && tid < 256) h2s[tn & 1][(tid >> 4) * 20 + (tid & 15)] = vn;
    __syncthreads();
  }
}

// ---------------------------------------------------------------------------
// 4-stage pipeline, 128 co-resident WGs (role = blk>>5, batch = blk&31):
//   A(0): layer-1 scan         pre1 -> h1     (bufPre -> bufH)
//   M(1): W_ih1 matvec stream  h1   -> pre2   (bufH -> bufPre in-place; M
//         writes pre2[t-1] only after A published t+1 => A consumed pre1
//         rows <= t+2 => safe by margin 3)
//   B(2): layer-2 scan         pre2 -> h2     (bufPre -> bufH in-place; B
//         writes h2[t-1] only after M published t+2 => M read h1 rows <= t+3)
//   F(3): fc+sigmoid stream    h2   -> out
// Acyclic waits, full-depth buffers (no backpressure), 128 WGs x 16 waves
// all resident on 256 CUs => spin-waits always make progress.
// ---------------------------------------------------------------------------
__global__ __attribute__((amdgpu_flat_work_group_size(1024, 1024),
                          amdgpu_waves_per_eu(4, 4)))
void pipeline(float* bufPre, float* bufH,
              const float* __restrict__ W_hh0,
              const float* __restrict__ W_ih1,
              const float* __restrict__ b_ih1, const float* __restrict__ b_hh1,
              const float* __restrict__ W_hh1,
              const float* __restrict__ fcW, const float* __restrict__ fcb,
              float* __restrict__ outp) {
  __shared__ float shpool[2][320];
  const int blk = blockIdx.x, role = blk >> 5, b = blk & 31;
  int* Af = g_flags + (0 * 32 + b) * FS;
  int* Mf = g_flags + (1 * 32 + b) * FS;
  int* Bf = g_flags + (2 * 32 + b) * FS;

  if (role == 0) {
    scan_role<false>(bufPre, W_hh0, bufH, nullptr, Af, b, shpool);
  } else if (role == 1) {
    mid_role(bufH, W_ih1, b_ih1, b_hh1, bufPre, Af, Mf, b, shpool);
  } else if (role == 2) {
    scan_role<true>(bufPre, W_hh1, bufH, Mf, Bf, b, shpool);
  } else {
    fc_role(bufH, fcW, fcb, outp, Bf, b, shpool);
  }
}

// ---------------------------------------------------------------------------
extern "C" void kernel_launch(void* const* d_in, const int* in_sizes, int n_in,
                              void* d_out, int out_size, void* d_ws, size_t ws_size,
                              hipStream_t stream) {
  const float* input = (const float*)d_in[0];
  const float* W_ih0 = (const float*)d_in[1];
  const float* W_hh0 = (const float*)d_in[2];
  const float* b_ih0 = (const float*)d_in[3];
  const float* b_hh0 = (const float*)d_in[4];
  const float* W_ih1 = (const float*)d_in[5];
  const float* W_hh1 = (const float*)d_in[6];
  const float* b_ih1 = (const float*)d_in[7];
  const float* b_hh1 = (const float*)d_in[8];
  const float* fc_W  = (const float*)d_in[9];
  const float* fc_b  = (const float*)d_in[10];
  float* out = (float*)d_out;

  // Workspace layout identical to the verified R1 kernel: 2 * M * H floats.
  float* bufPre = (float*)d_ws;               // pre1, later pre2 (in-place)
  float* bufH   = bufPre + (size_t)M * H;     // h1,   later h2   (in-place)

  zero_flags<<<1, 256, 0, stream>>>();
  gemm_pre<IN><<<(int)(M / 16), 256, 0, stream>>>(input, W_ih0, b_ih0, b_hh0, bufPre);
  pipeline<<<128, 1024, 0, stream>>>(bufPre, bufH, W_hh0, W_ih1, b_ih1, b_hh1,
                                     W_hh1, fc_W, fc_b, out);
}

// Round 4
// 3603.348 us; speedup vs baseline: 2.3649x; 2.3649x over previous
//
#include <hip/hip_runtime.h>

// Problem constants (match reference)
constexpr int Bsz = 32;
constexpr int T   = 4096;
constexpr int P   = 64;
constexpr int IN  = 128;
constexpr int H   = 256;
constexpr long M  = (long)Bsz * T;   // 131072 rows
constexpr int FS  = 16;              // flag padding stride (ints, 64 B)
constexpr int C   = 16;              // pipeline chunk: rows per flag publish
constexpr int NC  = T / C;           // 256 chunks
constexpr int RW  = 320;             // padded LDS row: 16 slices x (16+4)

// Progress flags in device-global memory (ws layout unchanged vs R1).
// flag==v means "rows 0..v-1 of my output stream are globally visible".
__device__ int g_flags[3 * 32 * FS];

__global__ void zero_flags() {
  for (int i = threadIdx.x; i < 3 * 32 * FS; i += 256) g_flags[i] = 0;
}

// ---------------------------------------------------------------------------
// K1: out[m][j] = sum_c X[m][c] * W[j][c] + b1[j] + b2[j]   (layer-1 input GEMM)
// ---------------------------------------------------------------------------
template <int K>
__global__ __launch_bounds__(256) void gemm_pre(
    const float* __restrict__ X, const float* __restrict__ W,
    const float* __restrict__ b1, const float* __restrict__ b2,
    float* __restrict__ out) {
  constexpr int K4 = K / 4;
  __shared__ float4 a4[16][K4];
  __shared__ float  wch[256][33];
  const int tid = threadIdx.x;
  const long m0 = (long)blockIdx.x * 16;

  const float4* X4 = (const float4*)X;
#pragma unroll
  for (int i = 0; i < (16 * K4) / 256; ++i) {
    int idx = tid + 256 * i;
    int r = idx / K4, c = idx % K4;
    a4[r][c] = X4[(m0 + r) * K4 + c];
  }

  const int j = tid;
  const float bsum = b1[j] + b2[j];
  float acc[16];
#pragma unroll
  for (int r = 0; r < 16; ++r) acc[r] = 0.f;

  const float4* W4v = (const float4*)W;
  for (int kc = 0; kc < K4; kc += 8) {
    __syncthreads();
#pragma unroll
    for (int i = 0; i < 8; ++i) {
      int idx = tid + 256 * i;
      int jr = idx >> 3, c = idx & 7;
      float4 t4 = W4v[(long)jr * K4 + kc + c];
      wch[jr][4 * c + 0] = t4.x; wch[jr][4 * c + 1] = t4.y;
      wch[jr][4 * c + 2] = t4.z; wch[jr][4 * c + 3] = t4.w;
    }
    __syncthreads();
#pragma unroll
    for (int i4 = 0; i4 < 8; ++i4) {
      float wx = wch[j][4 * i4 + 0], wy = wch[j][4 * i4 + 1];
      float wz = wch[j][4 * i4 + 2], ww = wch[j][4 * i4 + 3];
#pragma unroll
      for (int r = 0; r < 16; ++r) {
        float4 av = a4[r][kc + i4];
        acc[r] += wx * av.x + wy * av.y + wz * av.z + ww * av.w;
      }
    }
  }
#pragma unroll
  for (int r = 0; r < 16; ++r)
    out[(m0 + r) * H + j] = acc[r] + bsum;
}

// ---------------------------------------------------------------------------
// Cross-WG primitives (agent scope = coherent across per-XCD L2s).
// ---------------------------------------------------------------------------
__device__ __forceinline__ float gload(const float* p) {
  return __hip_atomic_load(const_cast<float*>(p), __ATOMIC_RELAXED,
                           __HIP_MEMORY_SCOPE_AGENT);
}
__device__ __forceinline__ void gstore(float* p, float v) {
  __hip_atomic_store(p, v, __ATOMIC_RELAXED, __HIP_MEMORY_SCOPE_AGENT);
}
__device__ __forceinline__ void wait_ge(const int* f, int target, int& seen) {
  if (seen >= target) return;
  int v = __hip_atomic_load(const_cast<int*>(f), __ATOMIC_ACQUIRE,
                            __HIP_MEMORY_SCOPE_AGENT);
  while (v < target) {
    __builtin_amdgcn_s_sleep(8);
    v = __hip_atomic_load(const_cast<int*>(f), __ATOMIC_ACQUIRE,
                          __HIP_MEMORY_SCOPE_AGENT);
  }
  seen = v;
}
__device__ __forceinline__ void publish(int* f, int v) {
  __hip_atomic_store(f, v, __ATOMIC_RELEASE, __HIP_MEMORY_SCOPE_AGENT);
}

// Light barrier: LDS-visibility only — does NOT drain vmcnt (in-flight
// global loads/stores ride across). Full barrier: drains everything
// (used once per chunk, right before flag publish — R3's proven publish
// sequence: all waves drain own stores -> s_barrier -> tid0 release-store).
__device__ __forceinline__ void bar_lds() {
  asm volatile("s_waitcnt lgkmcnt(0)\n\ts_barrier" ::: "memory");
}
__device__ __forceinline__ void bar_full() {
  asm volatile("s_waitcnt vmcnt(0) lgkmcnt(0)\n\ts_barrier" ::: "memory");
}

__device__ __forceinline__ int padw(int c) { return (c >> 4) * 20 + (c & 15); }

// ---------------------------------------------------------------------------
// Matvec: (4 j x 16 k) per thread. lane = jg(bits0-1) x ks(bits2-5).
// ---------------------------------------------------------------------------
struct WTile { float4 w[4][4]; };

__device__ __forceinline__ void load_wtile(const float* Wm, int wv, int jg,
                                           int ks, WTile& wt) {
  const float4* W4 = (const float4*)Wm;
#pragma unroll
  for (int r = 0; r < 4; ++r)
#pragma unroll
    for (int q = 0; q < 4; ++q)
      wt.w[r][q] = W4[(long)(wv * 16 + jg * 4 + r) * (H / 4) + ks * 4 + q];
#pragma unroll
  for (int r = 0; r < 4; ++r)
#pragma unroll
    for (int q = 0; q < 4; ++q)
      asm volatile("" : "+v"(wt.w[r][q].x), "+v"(wt.w[r][q].y),
                        "+v"(wt.w[r][q].z), "+v"(wt.w[r][q].w));
}

__device__ __forceinline__ float matvec_reduce(const WTile& wt, const float* hb,
                                               int bit4, int bit8) {
  float4 h0 = *(const float4*)(hb + 0);
  float4 h1 = *(const float4*)(hb + 4);
  float4 h2 = *(const float4*)(hb + 8);
  float4 h3 = *(const float4*)(hb + 12);
  float acc[4] = {0.f, 0.f, 0.f, 0.f};
#pragma unroll
  for (int r = 0; r < 4; ++r) {
    acc[r] += wt.w[r][0].x * h0.x + wt.w[r][0].y * h0.y +
              wt.w[r][0].z * h0.z + wt.w[r][0].w * h0.w;
    acc[r] += wt.w[r][1].x * h1.x + wt.w[r][1].y * h1.y +
              wt.w[r][1].z * h1.z + wt.w[r][1].w * h1.w;
    acc[r] += wt.w[r][2].x * h2.x + wt.w[r][2].y * h2.y +
              wt.w[r][2].z * h2.z + wt.w[r][2].w * h2.w;
    acc[r] += wt.w[r][3].x * h3.x + wt.w[r][3].y * h3.y +
              wt.w[r][3].z * h3.z + wt.w[r][3].w * h3.w;
  }
  __builtin_amdgcn_sched_barrier(0);
  float t0 = bit4 ? acc[0] : acc[2];
  float t1 = bit4 ? acc[1] : acc[3];
  float r0 = __int_as_float(__builtin_amdgcn_ds_swizzle(__float_as_int(t0), 0x101F));
  float r1 = __int_as_float(__builtin_amdgcn_ds_swizzle(__float_as_int(t1), 0x101F));
  float u0 = (bit4 ? acc[2] : acc[0]) + r0;
  float u1 = (bit4 ? acc[3] : acc[1]) + r1;
  float t2 = bit8 ? u0 : u1;
  float r2 = __int_as_float(__builtin_amdgcn_ds_swizzle(__float_as_int(t2), 0x201F));
  float s  = (bit8 ? u1 : u0) + r2;
  s += __int_as_float(__builtin_amdgcn_ds_swizzle(__float_as_int(s), 0x401F));
  s += __shfl_xor(s, 32, 64);
  return s;
}

// ---------------------------------------------------------------------------
// Role A/B: recurrent scan, chunked input ring. Per step: ring p-read + matvec
// + tanh + LDS h write + LDS-only barrier. Per chunk: one flag wait (staging
// loads issued a chunk ahead), one vmcnt drain + full barrier + one publish.
// ---------------------------------------------------------------------------
template <bool ATOMPRE>
__device__ __forceinline__ void scan_role(
    const float* prebuf, const float* Wm, float* houtb,
    const int* inflag, int* outflag, int b,
    float (*ring)[C][RW], float (*hdb)[RW]) {
  const int tid = threadIdx.x, lane = tid & 63, wv = tid >> 6;
  const int jg = lane & 3, ks = lane >> 2;
  const int bit4 = lane & 4, bit8 = lane & 8;
  const int jj2 = ((lane >> 1) & 2) | ((lane >> 3) & 1);

  WTile wt; load_wtile(Wm, wv, jg, ks, wt);
  const int  jmine = wv * 16 + jg * 4 + jj2;
  const long base  = (long)b * T * H;
  float* houtj = houtb + base + jmine;
  const int wr  = wv * 20 + (jg * 4 + jj2);
  const int prd = padw(jmine);
  const int src = tid >> 8;            // atomic staging row (0..3)
  const int sw  = padw(tid & 255);     // atomic staging word
  const int fr4 = (tid * 4) >> 8;      // float4 staging row
  const int fw4 = padw((tid * 4) & 255);

  if (tid < 2 * RW) ((float*)hdb)[tid] = 0.f;

  int seen = 0;
  // prologue: stage chunk 0 (rows 0..C-1)
  if (ATOMPRE) {
    wait_ge(inflag, C, seen);
    float v0 = gload(prebuf + base + tid);
    float v1 = gload(prebuf + base + 1024 + tid);
    float v2 = gload(prebuf + base + 2048 + tid);
    float v3 = gload(prebuf + base + 3072 + tid);
    ring[0][src][sw] = v0;      ring[0][src + 4][sw] = v1;
    ring[0][src + 8][sw] = v2;  ring[0][src + 12][sw] = v3;
  } else {
    float4 v = ((const float4*)(prebuf + base))[tid];
    *(float4*)&ring[0][fr4][fw4] = v;
  }
  bar_full();

#pragma unroll 1
  for (int k = 0; k < NC; ++k) {
    const int kn = k + 1;
    const bool more = (kn < NC);
    float s0 = 0.f, s1 = 0.f, s2 = 0.f, s3 = 0.f;
    float4 sv = {0.f, 0.f, 0.f, 0.f};
    if (more) {      // issue next-chunk staging loads (latency hidden by C steps)
      const float* nb = prebuf + base + (long)kn * C * H;
      if (ATOMPRE) {
        wait_ge(inflag, (kn + 1) * C, seen);
        s0 = gload(nb + tid);        s1 = gload(nb + 1024 + tid);
        s2 = gload(nb + 2048 + tid); s3 = gload(nb + 3072 + tid);
      } else {
        sv = ((const float4*)nb)[tid];
      }
    }
#pragma unroll 2
    for (int r = 0; r < C; ++r) {      // t = k*C + r; k*C even => t&1 == r&1
      const int t = k * C + r;
      float p = ring[k & 1][r][prd];
      float s = matvec_reduce(wt, hdb[r & 1] + ks * 20, bit4, bit8);
      float x = p + s;
      float e = __expf(2.f * x);
      float hn = 1.f - 2.f * __builtin_amdgcn_rcpf(e + 1.f);  // tanh(x)
      if (lane < 16) {
        hdb[(r + 1) & 1][wr] = hn;
        gstore(houtj + (long)t * H, hn);   // fire-and-forget, drained per chunk
      }
      if (r != C - 1) bar_lds();
    }
    if (more) {
      if (ATOMPRE) {
        ring[kn & 1][src][sw] = s0;      ring[kn & 1][src + 4][sw] = s1;
        ring[kn & 1][src + 8][sw] = s2;  ring[kn & 1][src + 12][sw] = s3;
      } else {
        *(float4*)&ring[kn & 1][fr4][fw4] = sv;
      }
    }
    bar_full();                          // drain h-row gstores + staging ds_writes
    if (tid == 0) publish(outflag, kn * C);
  }
}

// ---------------------------------------------------------------------------
// Role M: pre2[t] = W_ih1 @ h1[t] + b. No recurrent state -> no per-step
// barrier; C rows back-to-back per chunk.
// ---------------------------------------------------------------------------
__device__ __forceinline__ void mid_role(
    const float* h1b, const float* Wm, const float* bi, const float* bh,
    float* pre2b, const int* Af, int* Mf, int b, float (*ring)[C][RW]) {
  const int tid = threadIdx.x, lane = tid & 63, wv = tid >> 6;
  const int jg = lane & 3, ks = lane >> 2;
  const int bit4 = lane & 4, bit8 = lane & 8;
  const int jj2 = ((lane >> 1) & 2) | ((lane >> 3) & 1);

  WTile wt; load_wtile(Wm, wv, jg, ks, wt);
  const int  jmine = wv * 16 + jg * 4 + jj2;
  const float bsum = bi[jmine] + bh[jmine];
  const long base  = (long)b * T * H;
  float* poutj = pre2b + base + jmine;
  const int src = tid >> 8, sw = padw(tid & 255);

  int seen = 0;
  wait_ge(Af, C, seen);
  {
    float v0 = gload(h1b + base + tid);
    float v1 = gload(h1b + base + 1024 + tid);
    float v2 = gload(h1b + base + 2048 + tid);
    float v3 = gload(h1b + base + 3072 + tid);
    ring[0][src][sw] = v0;      ring[0][src + 4][sw] = v1;
    ring[0][src + 8][sw] = v2;  ring[0][src + 12][sw] = v3;
  }
  bar_full();

#pragma unroll 1
  for (int k = 0; k < NC; ++k) {
    const int kn = k + 1;
    const bool more = (kn < NC);
    float s0 = 0.f, s1 = 0.f, s2 = 0.f, s3 = 0.f;
    if (more) {
      wait_ge(Af, (kn + 1) * C, seen);
      const float* nb = h1b + base + (long)kn * C * H;
      s0 = gload(nb + tid);        s1 = gload(nb + 1024 + tid);
      s2 = gload(nb + 2048 + tid); s3 = gload(nb + 3072 + tid);
    }
#pragma unroll 2
    for (int r = 0; r < C; ++r) {
      const int t = k * C + r;
      float s = matvec_reduce(wt, ring[k & 1][r] + ks * 20, bit4, bit8) + bsum;
      if (lane < 16) gstore(poutj + (long)t * H, s);
    }
    if (more) {
      ring[kn & 1][src][sw] = s0;      ring[kn & 1][src + 4][sw] = s1;
      ring[kn & 1][src + 8][sw] = s2;  ring[kn & 1][src + 12][sw] = s3;
    }
    bar_full();
    if (tid == 0) publish(Mf, kn * C);
  }
}

// ---------------------------------------------------------------------------
// Role F: out[b*T+t][p] = sigmoid(h2[t]·fcW[p] + fcb[p]). Chunk-synced ring,
// no per-step barrier, plain output stores.
// ---------------------------------------------------------------------------
__device__ __forceinline__ void fc_role(
    const float* h2b, const float* fcWm, const float* fcbv, float* outp,
    const int* Bf, int b, float (*ring)[C][RW]) {
  const int tid = threadIdx.x, lane = tid & 63, wv = tid >> 6;
  const int jg = lane & 3, ks = lane >> 2;
  const int p = wv * 4 + jg;

  const float4* W4 = (const float4*)fcWm;
  float4 fw[4];
#pragma unroll
  for (int q = 0; q < 4; ++q) fw[q] = W4[(long)p * (H / 4) + ks * 4 + q];
  const float fb = fcbv[p];
  const long base  = (long)b * T * H;
  const long obase = (long)b * T * P;
  const int src = tid >> 8, sw = padw(tid & 255);

  int seen = 0;
  wait_ge(Bf, C, seen);
  {
    float v0 = gload(h2b + base + tid);
    float v1 = gload(h2b + base + 1024 + tid);
    float v2 = gload(h2b + base + 2048 + tid);
    float v3 = gload(h2b + base + 3072 + tid);
    ring[0][src][sw] = v0;      ring[0][src + 4][sw] = v1;
    ring[0][src + 8][sw] = v2;  ring[0][src + 12][sw] = v3;
  }
  bar_full();

#pragma unroll 1
  for (int k = 0; k < NC; ++k) {
    const int kn = k + 1;
    const bool more = (kn < NC);
    float s0 = 0.f, s1 = 0.f, s2 = 0.f, s3 = 0.f;
    if (more) {
      wait_ge(Bf, (kn + 1) * C, seen);
      const float* nb = h2b + base + (long)kn * C * H;
      s0 = gload(nb + tid);        s1 = gload(nb + 1024 + tid);
      s2 = gload(nb + 2048 + tid); s3 = gload(nb + 3072 + tid);
    }
#pragma unroll 2
    for (int r = 0; r < C; ++r) {
      const int t = k * C + r;
      const float* hb = ring[k & 1][r] + ks * 20;
      float4 h0 = *(const float4*)(hb + 0);
      float4 h1 = *(const float4*)(hb + 4);
      float4 h2 = *(const float4*)(hb + 8);
      float4 h3 = *(const float4*)(hb + 12);
      float s = fw[0].x * h0.x + fw[0].y * h0.y + fw[0].z * h0.z + fw[0].w * h0.w
              + fw[1].x * h1.x + fw[1].y * h1.y + fw[1].z * h1.z + fw[1].w * h1.w
              + fw[2].x * h2.x + fw[2].y * h2.y + fw[2].z * h2.z + fw[2].w * h2.w
              + fw[3].x * h3.x + fw[3].y * h3.y + fw[3].z * h3.z + fw[3].w * h3.w;
      s += __int_as_float(__builtin_amdgcn_ds_swizzle(__float_as_int(s), 0x101F));
      s += __int_as_float(__builtin_amdgcn_ds_swizzle(__float_as_int(s), 0x201F));
      s += __int_as_float(__builtin_amdgcn_ds_swizzle(__float_as_int(s), 0x401F));
      s += __shfl_xor(s, 32, 64);
      float xx = s + fb;
      float sig = __builtin_amdgcn_rcpf(1.f + __expf(-xx));
      if (lane < 4) outp[obase + (long)t * P + wv * 4 + lane] = sig;
    }
    if (more) {
      ring[kn & 1][src][sw] = s0;      ring[kn & 1][src + 4][sw] = s1;
      ring[kn & 1][src + 8][sw] = s2;  ring[kn & 1][src + 12][sw] = s3;
    }
    bar_full();
  }
}

// ---------------------------------------------------------------------------
// 4-stage pipeline, 128 co-resident WGs (role = blk>>5, batch = blk&31).
// Chunked handoff: consumer chunk k waits producer flag >= (k+2)*C (stages one
// chunk ahead) => each stage lags its producer by 2 chunks (fill ~96 steps).
// In-place reuse stays safe: a region is consumed >=2 chunks before overwrite.
// ---------------------------------------------------------------------------
__global__ __attribute__((amdgpu_flat_work_group_size(1024, 1024),
                          amdgpu_waves_per_eu(4, 4)))
void pipeline(float* bufPre, float* bufH,
              const float* __restrict__ W_hh0,
              const float* __restrict__ W_ih1,
              const float* __restrict__ b_ih1, const float* __restrict__ b_hh1,
              const float* __restrict__ W_hh1,
              const float* __restrict__ fcW, const float* __restrict__ fcb,
              float* __restrict__ outp) {
  __shared__ float ring[2][C][RW];   // 40 KiB input-stream double buffer
  __shared__ float hdb[2][RW];       // 2.5 KiB recurrent-state double buffer
  const int blk = blockIdx.x, role = blk >> 5, b = blk & 31;
  int* Af = g_flags + (0 * 32 + b) * FS;
  int* Mf = g_flags + (1 * 32 + b) * FS;
  int* Bf = g_flags + (2 * 32 + b) * FS;

  if (role == 0) {
    scan_role<false>(bufPre, W_hh0, bufH, nullptr, Af, b, ring, hdb);
  } else if (role == 1) {
    mid_role(bufH, W_ih1, b_ih1, b_hh1, bufPre, Af, Mf, b, ring);
  } else if (role == 2) {
    scan_role<true>(bufPre, W_hh1, bufH, Mf, Bf, b, ring, hdb);
  } else {
    fc_role(bufH, fcW, fcb, outp, Bf, b, ring);
  }
}

// ---------------------------------------------------------------------------
extern "C" void kernel_launch(void* const* d_in, const int* in_sizes, int n_in,
                              void* d_out, int out_size, void* d_ws, size_t ws_size,
                              hipStream_t stream) {
  const float* input = (const float*)d_in[0];
  const float* W_ih0 = (const float*)d_in[1];
  const float* W_hh0 = (const float*)d_in[2];
  const float* b_ih0 = (const float*)d_in[3];
  const float* b_hh0 = (const float*)d_in[4];
  const float* W_ih1 = (const float*)d_in[5];
  const float* W_hh1 = (const float*)d_in[6];
  const float* b_ih1 = (const float*)d_in[7];
  const float* b_hh1 = (const float*)d_in[8];
  const float* fc_W  = (const float*)d_in[9];
  const float* fc_b  = (const float*)d_in[10];
  float* out = (float*)d_out;

  // Workspace layout identical to the verified R1 kernel: 2 * M * H floats.
  float* bufPre = (float*)d_ws;               // pre1, later pre2 (in-place)
  float* bufH   = bufPre + (size_t)M * H;     // h1,   later h2   (in-place)

  zero_flags<<<1, 256, 0, stream>>>();
  gemm_pre<IN><<<(int)(M / 16), 256, 0, stream>>>(input, W_ih0, b_ih0, b_hh0, bufPre);
  pipeline<<<128, 1024, 0, stream>>>(bufPre, bufH, W_hh0, W_ih1, b_ih1, b_hh1,
                                     W_hh1, fc_W, fc_b, out);
}